// Round 1
// 697.806 us; speedup vs baseline: 1.0188x; 1.0188x over previous
//
#include <hip/hip_runtime.h>
#include <hip/hip_bf16.h>

typedef __bf16 bf16x8 __attribute__((ext_vector_type(8)));
typedef float  f32x4  __attribute__((ext_vector_type(4)));

// One wave = 16 feature rows. Block = 4 waves = 64 rows. N % 64 == 0 (1e6 = 64*15625).
// OPERAND SWAP vs previous version: prototypes are the MFMA *A* operand, features are *B*.
//   A-fragment: lane holds A[m=lane&15][k=(lane>>4)*8+j]  -> proto[t*16+m][k]
//   B-fragment: lane holds B[k=(lane>>4)*8+j][n=lane&15]  -> feat[rowBase+n][k]
//   C/D layout (m89-verified): col = lane&15 (feature), row = (lane>>4)*4 + reg (proto).
// => each lane owns 16 logits of ONE feature row, 4 consecutive protos per f32x4 reg:
//    - softmax: 15 local ops + 2 shuffles (was 32 shuffles)
//    - stores: 8x global_store_dwordx4 (was 32x scalar dword)
__global__ __launch_bounds__(256) void proto_assign(
    const float* __restrict__ feat,
    const float* __restrict__ proto,
    float* __restrict__ logits,
    float* __restrict__ probs)
{
    const int lane = threadIdx.x & 63;
    const int wave = threadIdx.x >> 6;
    const int m    = lane & 15;
    const int q    = lane >> 4;

    // ---- A fragments: prototypes [K=64 protos][D=64], already unit-norm ----
    bf16x8 plo[4], phi[4];
#pragma unroll
    for (int t = 0; t < 4; ++t) {
        const float* p = proto + (t * 16 + m) * 64 + q * 8;
        f32x4 p0 = *(const f32x4*)(p + 0);
        f32x4 p1 = *(const f32x4*)(p + 4);
        f32x4 p2 = *(const f32x4*)(p + 32);
        f32x4 p3 = *(const f32x4*)(p + 36);
#pragma unroll
        for (int i = 0; i < 4; ++i) {
            plo[t][i]     = (__bf16)p0[i];
            plo[t][4 + i] = (__bf16)p1[i];
            phi[t][i]     = (__bf16)p2[i];
            phi[t][4 + i] = (__bf16)p3[i];
        }
    }

    // ---- B: 16 feature rows, each lane loads its own fragment slots (fp32) ----
    const long long rowBase = (long long)blockIdx.x * 64 + wave * 16;
    const float* f = feat + (rowBase + m) * 64 + q * 8;
    f32x4 a0 = *(const f32x4*)(f + 0);
    f32x4 a1 = *(const f32x4*)(f + 4);
    f32x4 a2 = *(const f32x4*)(f + 32);
    f32x4 a3 = *(const f32x4*)(f + 36);

    // ---- L2 norm across the 4 q-groups holding this row ----
    float ss = 0.f;
#pragma unroll
    for (int i = 0; i < 4; ++i)
        ss += a0[i]*a0[i] + a1[i]*a1[i] + a2[i]*a2[i] + a3[i]*a3[i];
    ss += __shfl_xor(ss, 16);
    ss += __shfl_xor(ss, 32);
    // x / max(||x||, eps) then / tau  ==> scale = 5 / max(||x||, 1e-8)
    const float scale = 5.0f / fmaxf(sqrtf(ss), 1e-8f);

    bf16x8 flo, fhi;
#pragma unroll
    for (int i = 0; i < 4; ++i) {
        flo[i]     = (__bf16)(a0[i] * scale);
        flo[4 + i] = (__bf16)(a1[i] * scale);
        fhi[i]     = (__bf16)(a2[i] * scale);
        fhi[4 + i] = (__bf16)(a3[i] * scale);
    }

    // ---- 8 MFMAs: Sᵀ tiles — 64 protos (rows) x 16 features (cols), K=64 ----
    f32x4 acc[4] = {};
#pragma unroll
    for (int t = 0; t < 4; ++t)
        acc[t] = __builtin_amdgcn_mfma_f32_16x16x32_bf16(plo[t], flo, acc[t], 0, 0, 0);
#pragma unroll
    for (int t = 0; t < 4; ++t)
        acc[t] = __builtin_amdgcn_mfma_f32_16x16x32_bf16(phi[t], fhi, acc[t], 0, 0, 0);

    // ---- softmax over 64 protos: lane holds 16 of them; row split across q-groups ----
    float mx = fmaxf(fmaxf(acc[0][0], acc[0][1]), fmaxf(acc[0][2], acc[0][3]));
#pragma unroll
    for (int t = 1; t < 4; ++t)
        mx = fmaxf(mx, fmaxf(fmaxf(acc[t][0], acc[t][1]), fmaxf(acc[t][2], acc[t][3])));
    mx = fmaxf(mx, __shfl_xor(mx, 16));
    mx = fmaxf(mx, __shfl_xor(mx, 32));

    f32x4 ex[4];
    float s = 0.f;
#pragma unroll
    for (int t = 0; t < 4; ++t) {
#pragma unroll
        for (int r = 0; r < 4; ++r) {
            ex[t][r] = __expf(acc[t][r] - mx);
            s += ex[t][r];
        }
    }
    s += __shfl_xor(s, 16);
    s += __shfl_xor(s, 32);
    const float rs = 1.0f / s;

    // ---- vectorized stores: lane writes row (rowBase+m), cols t*16 + q*4 .. +3 ----
    float* lp = logits + (rowBase + m) * 64 + q * 4;
    float* pp = probs  + (rowBase + m) * 64 + q * 4;
#pragma unroll
    for (int t = 0; t < 4; ++t) {
        *(f32x4*)(lp + t * 16) = acc[t];
        f32x4 pr;
#pragma unroll
        for (int r = 0; r < 4; ++r) pr[r] = ex[t][r] * rs;
        *(f32x4*)(pp + t * 16) = pr;
    }
}

extern "C" void kernel_launch(void* const* d_in, const int* in_sizes, int n_in,
                              void* d_out, int out_size, void* d_ws, size_t ws_size,
                              hipStream_t stream) {
    const float* feat  = (const float*)d_in[0];
    const float* proto = (const float*)d_in[1];
    const int N = in_sizes[0] / 64;            // 1,000,000 rows; divisible by 64
    float* logits = (float*)d_out;
    float* probs  = logits + (long long)N * 64;
    proto_assign<<<N / 64, 256, 0, stream>>>(feat, proto, logits, probs);
}